// Round 1
// baseline (831.795 us; speedup 1.0000x reference)
//
#include <hip/hip_runtime.h>

// Problem constants (from reference)
#define LD_   16384
#define LU_   65536
#define N_    8
#define DIN   256
#define DOUT  128
#define K_    3
#define M_    (LD_ * N_)   // 131072 rows through the MLP

#define TM 32              // rows per block in the MLP kernel

// ---------------------------------------------------------------------------
// Kernel 1: h[m, :] = relu(down[m, :] @ W1 + b1) @ W2 + b2   (fp32)
// Block: 256 threads, handles TM=32 consecutive rows.
// Thread t: column e = t & 127, rows r0..r0+15 (r0 = (t>>7)*16).
// down tile staged in LDS (contiguous 32 KiB), LDS row reads are wave-uniform
// broadcasts; k unrolled by 4 so reads are ds_read_b128.
// ---------------------------------------------------------------------------
__global__ __launch_bounds__(256) void knn_mlp_kernel(
    const float* __restrict__ down, const float* __restrict__ W1,
    const float* __restrict__ b1,   const float* __restrict__ W2,
    const float* __restrict__ b2,   float* __restrict__ h)
{
    __shared__ float s_down[TM * DIN];   // 32 KiB
    __shared__ float s_h1[TM * DOUT];    // 16 KiB

    const int t  = threadIdx.x;
    const int m0 = blockIdx.x * TM;

    // Cooperative load of the down tile: rows m0..m0+31 are contiguous memory.
    {
        const float4* src = (const float4*)(down + (size_t)m0 * DIN);
        float4* dst = (float4*)s_down;
        #pragma unroll
        for (int i = 0; i < (TM * DIN / 4) / 256; ++i)   // 8 iterations
            dst[t + i * 256] = src[t + i * 256];
    }
    __syncthreads();

    const int e  = t & 127;
    const int r0 = (t >> 7) * (TM / 2);

    // ---- layer 1: 256 -> 128, relu ----
    float acc[TM / 2];
    {
        const float bias = b1[e];
        #pragma unroll
        for (int r = 0; r < TM / 2; ++r) acc[r] = bias;
    }
    for (int k4 = 0; k4 < DIN / 4; ++k4) {
        const float w0 = W1[(k4 * 4 + 0) * DOUT + e];
        const float w1 = W1[(k4 * 4 + 1) * DOUT + e];
        const float w2 = W1[(k4 * 4 + 2) * DOUT + e];
        const float w3 = W1[(k4 * 4 + 3) * DOUT + e];
        #pragma unroll
        for (int r = 0; r < TM / 2; ++r) {
            const float4 d = *(const float4*)&s_down[(r0 + r) * DIN + k4 * 4];
            acc[r] = fmaf(d.x, w0, acc[r]);
            acc[r] = fmaf(d.y, w1, acc[r]);
            acc[r] = fmaf(d.z, w2, acc[r]);
            acc[r] = fmaf(d.w, w3, acc[r]);
        }
    }
    #pragma unroll
    for (int r = 0; r < TM / 2; ++r)
        s_h1[(r0 + r) * DOUT + e] = fmaxf(acc[r], 0.0f);
    __syncthreads();

    // ---- layer 2: 128 -> 128 ----
    float acc2[TM / 2];
    {
        const float bias = b2[e];
        #pragma unroll
        for (int r = 0; r < TM / 2; ++r) acc2[r] = bias;
    }
    for (int k4 = 0; k4 < DOUT / 4; ++k4) {
        const float w0 = W2[(k4 * 4 + 0) * DOUT + e];
        const float w1 = W2[(k4 * 4 + 1) * DOUT + e];
        const float w2 = W2[(k4 * 4 + 2) * DOUT + e];
        const float w3 = W2[(k4 * 4 + 3) * DOUT + e];
        #pragma unroll
        for (int r = 0; r < TM / 2; ++r) {
            const float4 d = *(const float4*)&s_h1[(r0 + r) * DOUT + k4 * 4];
            acc2[r] = fmaf(d.x, w0, acc2[r]);
            acc2[r] = fmaf(d.y, w1, acc2[r]);
            acc2[r] = fmaf(d.z, w2, acc2[r]);
            acc2[r] = fmaf(d.w, w3, acc2[r]);
        }
    }
    #pragma unroll
    for (int r = 0; r < TM / 2; ++r)
        h[(size_t)(m0 + r0 + r) * DOUT + e] = acc2[r];
}

// ---------------------------------------------------------------------------
// Kernel 2: out[lu, n, :] = up[lu, n, :] + mean_k h[idx[lu,n,k], n, :]
// One wave (64 lanes) per (lu, n) pair; each lane handles a float2 (2 of 128).
// Gather reads are coalesced 512 B wave reads at random rows of h.
// ---------------------------------------------------------------------------
__global__ __launch_bounds__(256) void knn_gather_kernel(
    const float* __restrict__ up, const int* __restrict__ idx,
    const float* __restrict__ h,  float* __restrict__ out)
{
    const int wave = threadIdx.x >> 6;
    const int lane = threadIdx.x & 63;
    const size_t pair = (size_t)blockIdx.x * 4 + wave;   // = lu * N_ + n
    const int n = (int)(pair & (N_ - 1));

    const int* ip = idx + pair * K_;
    const int i0 = ip[0];
    const int i1 = ip[1];
    const int i2 = ip[2];

    const float2* h2 = (const float2*)h;
    const float2 a = h2[((size_t)i0 * N_ + n) * (DOUT / 2) + lane];
    const float2 b = h2[((size_t)i1 * N_ + n) * (DOUT / 2) + lane];
    const float2 c = h2[((size_t)i2 * N_ + n) * (DOUT / 2) + lane];
    const float2 u = ((const float2*)up)[pair * (DOUT / 2) + lane];

    float2 o;
    o.x = u.x + (a.x + b.x + c.x) * (1.0f / 3.0f);
    o.y = u.y + (a.y + b.y + c.y) * (1.0f / 3.0f);
    ((float2*)out)[pair * (DOUT / 2) + lane] = o;
}

// ---------------------------------------------------------------------------
extern "C" void kernel_launch(void* const* d_in, const int* in_sizes, int n_in,
                              void* d_out, int out_size, void* d_ws, size_t ws_size,
                              hipStream_t stream)
{
    const float* down = (const float*)d_in[0];
    const float* up   = (const float*)d_in[1];
    const int*   idx  = (const int*)d_in[2];
    const float* W1   = (const float*)d_in[3];
    const float* b1   = (const float*)d_in[4];
    const float* W2   = (const float*)d_in[5];
    const float* b2   = (const float*)d_in[6];
    float* out = (float*)d_out;
    float* h   = (float*)d_ws;   // M_ * DOUT fp32 = 64 MiB

    knn_mlp_kernel<<<M_ / TM, 256, 0, stream>>>(down, W1, b1, W2, b2, h);
    knn_gather_kernel<<<(LU_ * N_) / 4, 256, 0, stream>>>(up, idx, h, out);
}

// Round 2
// 586.098 us; speedup vs baseline: 1.4192x; 1.4192x over previous
//
#include <hip/hip_runtime.h>

#define LD_   16384
#define LU_   65536
#define N_    8
#define DIN   256
#define DOUT  128
#define K_    3
#define M_    (LD_ * N_)   // 131072 rows through the MLP

typedef short bf16x8 __attribute__((ext_vector_type(8)));
typedef float f32x4  __attribute__((ext_vector_type(4)));

// fp32 -> bf16 round-to-nearest-even (inputs finite, no NaN handling)
__device__ __forceinline__ unsigned short f2bf(float f) {
    unsigned int x = __float_as_uint(f);
    x += 0x7fffu + ((x >> 16) & 1u);
    return (unsigned short)(x >> 16);
}

__device__ __forceinline__ bf16x8 ld_bf16x8(const unsigned short* p) {
    // two aligned 8 B LDS reads (b64); p is 8 B aligned by construction
    const short4 lo = *(const short4*)p;
    const short4 hi = *(const short4*)(p + 4);
    bf16x8 r = {lo.x, lo.y, lo.z, lo.w, hi.x, hi.y, hi.z, hi.w};
    return r;
}

// padded LDS strides (in bf16 elements): keep 16 B k-offsets 8 B-aligned,
// stride_words % 32 == 2 -> 2-way bank aliasing (free on CDNA4, m136)
#define W1_STRIDE 264   // k-dim 256 + 8
#define W2_STRIDE 132   // k-dim 128 + 4
#define H1_STRIDE 132

// ---------------------------------------------------------------------------
// MLP: h[m,:] = relu(down[m,:] @ W1 + b1) @ W2 + b2, h stored as bf16.
// 256 persistent blocks x 512 threads (8 waves). Each block: stage W1^T/W2^T
// in LDS once, then 4 passes of 128 rows (16 rows per wave).
// MFMA 16x16x32 bf16. A-frags: lane lm=l&15 -> row, lg=l>>4 -> k-group.
// ---------------------------------------------------------------------------
__global__ __launch_bounds__(512, 2) void knn_mlp_mfma(
    const float* __restrict__ down, const float* __restrict__ W1,
    const float* __restrict__ b1,   const float* __restrict__ W2,
    const float* __restrict__ b2,   unsigned short* __restrict__ h)
{
    __shared__ unsigned short sW1t[DOUT * W1_STRIDE];        // [n][k] 66 KiB
    __shared__ unsigned short sW2t[DOUT * W2_STRIDE];        // [n][k] 33 KiB
    __shared__ unsigned short sH[8][16 * H1_STRIDE];         // per-wave 33 KiB

    const int tid = threadIdx.x;

    // ---- stage W1^T (bf16, transposed) ----
    #pragma unroll
    for (int it = 0; it < 16; ++it) {
        const int fid = it * 512 + tid;              // 8192 float4s of W1
        const int k = fid >> 5, n4 = (fid & 31) * 4;
        const float4 w = ((const float4*)W1)[fid];
        sW1t[(n4 + 0) * W1_STRIDE + k] = f2bf(w.x);
        sW1t[(n4 + 1) * W1_STRIDE + k] = f2bf(w.y);
        sW1t[(n4 + 2) * W1_STRIDE + k] = f2bf(w.z);
        sW1t[(n4 + 3) * W1_STRIDE + k] = f2bf(w.w);
    }
    // ---- stage W2^T ----
    #pragma unroll
    for (int it = 0; it < 8; ++it) {
        const int fid = it * 512 + tid;              // 4096 float4s of W2
        const int k = fid >> 5, n4 = (fid & 31) * 4;
        const float4 w = ((const float4*)W2)[fid];
        sW2t[(n4 + 0) * W2_STRIDE + k] = f2bf(w.x);
        sW2t[(n4 + 1) * W2_STRIDE + k] = f2bf(w.y);
        sW2t[(n4 + 2) * W2_STRIDE + k] = f2bf(w.z);
        sW2t[(n4 + 3) * W2_STRIDE + k] = f2bf(w.w);
    }
    __syncthreads();

    const int wave = tid >> 6, lane = tid & 63;
    const int lm = lane & 15, lg = lane >> 4;
    unsigned short* hw = sH[wave];

    float b1r[8], b2r[8];
    #pragma unroll
    for (int nt = 0; nt < 8; ++nt) {
        b1r[nt] = b1[nt * 16 + lm];
        b2r[nt] = b2[nt * 16 + lm];
    }

    for (int pass = 0; pass < 4; ++pass) {
        const int chunk = blockIdx.x * 512 + pass * 128 + wave * 16;

        // ---- load 16 rows of down straight into A-fragments ----
        const float* dp = down + (size_t)(chunk + lm) * DIN + lg * 8;
        float4 raw[16];
        #pragma unroll
        for (int k = 0; k < 8; ++k) {
            raw[2 * k]     = *(const float4*)(dp + k * 32);
            raw[2 * k + 1] = *(const float4*)(dp + k * 32 + 4);
        }
        bf16x8 A1[8];
        #pragma unroll
        for (int k = 0; k < 8; ++k) {
            const float4 r0 = raw[2 * k], r1 = raw[2 * k + 1];
            bf16x8 a = {(short)f2bf(r0.x), (short)f2bf(r0.y), (short)f2bf(r0.z), (short)f2bf(r0.w),
                        (short)f2bf(r1.x), (short)f2bf(r1.y), (short)f2bf(r1.z), (short)f2bf(r1.w)};
            A1[k] = a;
        }

        // ---- layer 1: 256 -> 128 ----
        f32x4 acc[8];
        #pragma unroll
        for (int nt = 0; nt < 8; ++nt) acc[nt] = (f32x4){0.f, 0.f, 0.f, 0.f};
        #pragma unroll
        for (int k = 0; k < 8; ++k) {
            const int koff = k * 32 + lg * 8;
            #pragma unroll
            for (int nt = 0; nt < 8; ++nt) {
                const bf16x8 B = ld_bf16x8(&sW1t[(nt * 16 + lm) * W1_STRIDE + koff]);
                acc[nt] = __builtin_amdgcn_mfma_f32_16x16x32_bf16(A1[k], B, acc[nt], 0, 0, 0);
            }
        }

        // relu + bias -> per-wave LDS tile (C-layout -> [m][k] for layer 2)
        #pragma unroll
        for (int nt = 0; nt < 8; ++nt) {
            #pragma unroll
            for (int i = 0; i < 4; ++i) {
                float v = acc[nt][i] + b1r[nt];
                v = fmaxf(v, 0.0f);
                hw[(lg * 4 + i) * H1_STRIDE + nt * 16 + lm] = f2bf(v);
            }
        }
        __syncthreads();   // cross-lane LDS dependency (writes -> reads)

        // ---- layer 2: 128 -> 128 ----
        f32x4 acc2[8];
        #pragma unroll
        for (int nt = 0; nt < 8; ++nt) acc2[nt] = (f32x4){0.f, 0.f, 0.f, 0.f};
        #pragma unroll
        for (int k = 0; k < 4; ++k) {
            const int koff = k * 32 + lg * 8;
            const bf16x8 A2 = ld_bf16x8(&hw[lm * H1_STRIDE + koff]);
            #pragma unroll
            for (int nt = 0; nt < 8; ++nt) {
                const bf16x8 B = ld_bf16x8(&sW2t[(nt * 16 + lm) * W2_STRIDE + koff]);
                acc2[nt] = __builtin_amdgcn_mfma_f32_16x16x32_bf16(A2, B, acc2[nt], 0, 0, 0);
            }
        }

        // epilogue: + b2, cvt bf16, store to global h
        #pragma unroll
        for (int nt = 0; nt < 8; ++nt) {
            #pragma unroll
            for (int i = 0; i < 4; ++i) {
                const float v = acc2[nt][i] + b2r[nt];
                h[(size_t)(chunk + lg * 4 + i) * DOUT + nt * 16 + lm] = f2bf(v);
            }
        }
        __syncthreads();   // WAR: sH reused next pass
    }
}

// ---------------------------------------------------------------------------
// Gather: out[p,:] = up[p,:] + mean_k h_bf16[idx[p,k]*8 + n, :]
// One wave per 64 pairs (grid-stride free), 4-pair unroll -> 16 loads in
// flight. Lane covers 2 of 128 cols (one uint = 2 bf16 / one float2).
// ---------------------------------------------------------------------------
__global__ __launch_bounds__(256) void knn_gather(
    const float* __restrict__ up, const int* __restrict__ idx,
    const unsigned int* __restrict__ h32, float* __restrict__ out)
{
    const int wave = threadIdx.x >> 6, lane = threadIdx.x & 63;
    const long long wid  = (long long)blockIdx.x * 4 + wave;   // 8192 waves
    const long long base = wid * 64;                           // pairs/wave

    for (int p0 = 0; p0 < 64; p0 += 4) {
        const long long pair0 = base + p0;
        // 12 consecutive ints of idx (16 B aligned)
        const int4* ip = (const int4*)(idx + pair0 * 3);
        const int4 q0 = ip[0], q1 = ip[1], q2 = ip[2];
        const int id[4][3] = {{q0.x, q0.y, q0.z}, {q0.w, q1.x, q1.y},
                              {q1.z, q1.w, q2.x}, {q2.y, q2.z, q2.w}};

        unsigned int ga[4][3];
        float2 uu[4];
        #pragma unroll
        for (int u = 0; u < 4; ++u) {
            const long long pair = pair0 + u;
            const int n = (int)(pair & 7);
            ga[u][0] = h32[((size_t)id[u][0] * 8 + n) * 64 + lane];
            ga[u][1] = h32[((size_t)id[u][1] * 8 + n) * 64 + lane];
            ga[u][2] = h32[((size_t)id[u][2] * 8 + n) * 64 + lane];
            uu[u] = ((const float2*)up)[pair * 64 + lane];
        }
        #pragma unroll
        for (int u = 0; u < 4; ++u) {
            float sx = 0.f, sy = 0.f;
            #pragma unroll
            for (int j = 0; j < 3; ++j) {
                const unsigned int v = ga[u][j];
                sx += __uint_as_float(v << 16);
                sy += __uint_as_float(v & 0xffff0000u);
            }
            float2 o;
            o.x = uu[u].x + sx * (1.0f / 3.0f);
            o.y = uu[u].y + sy * (1.0f / 3.0f);
            ((float2*)out)[(pair0 + u) * 64 + lane] = o;
        }
    }
}

// ---------------------------------------------------------------------------
extern "C" void kernel_launch(void* const* d_in, const int* in_sizes, int n_in,
                              void* d_out, int out_size, void* d_ws, size_t ws_size,
                              hipStream_t stream)
{
    const float* down = (const float*)d_in[0];
    const float* up   = (const float*)d_in[1];
    const int*   idx  = (const int*)d_in[2];
    const float* W1   = (const float*)d_in[3];
    const float* b1   = (const float*)d_in[4];
    const float* W2   = (const float*)d_in[5];
    const float* b2   = (const float*)d_in[6];
    float* out = (float*)d_out;
    unsigned short* h = (unsigned short*)d_ws;   // M_ x 128 bf16 = 32 MiB

    knn_mlp_mfma<<<256, 512, 0, stream>>>(down, W1, b1, W2, b2, h);
    knn_gather<<<2048, 256, 0, stream>>>(up, idx, (const unsigned int*)h, out);
}